// Round 6
// baseline (145.378 us; speedup 1.0000x reference)
//
#include <hip/hip_runtime.h>

// WaveletLoss: 3-level Haar DWT + soft-threshold + weighted mean-abs-diff.
// B=64, C=1, H=W=512.
// R5: global_load_lds DMA probe. Read path via direct-to-LDS staging (no VGPR
// writeback) to test whether the ~3.1 TB/s read wall is the per-CU vector-load
// return queue. Block = 64 KB LDS (2 bufs x 2 inputs x 8x256 fp32 tile),
// double-buffered, one barrier per tile, loads in flight across compute.
// Compute: waves 0-1, lane = one 4x4 block; levels 1-2 in-lane, level 3 via
// __shfl_xor(1/2/3) in 4-lane groups (R1's verified pattern). No atomics.

#define IMG_W 512
#define N_BATCH 64

#define THR1 (50.0f / 255.0f)
#define THR2 (25.0f / 255.0f)
#define THR3 (12.5f / 255.0f)

#define NBLK 1024
#define NT   8          // tiles per block; 1024*8 = 8192 tiles of 8x256

typedef __attribute__((address_space(1))) const void* gas_t;
typedef __attribute__((address_space(3))) void*       las_t;

__device__ __forceinline__ float softthr(float x, float thr) {
    float m = fmaxf(fabsf(x) - thr, 0.0f);
    return copysignf(m, x);
}

__device__ __forceinline__ float detail_term(float p, float t, float thr) {
    return fabsf(softthr(p, thr) - softthr(t, thr));
}

__device__ __forceinline__ void haar_quad(float a, float b, float c, float d,
                                          float& cA, float& cH, float& cV, float& cD) {
    cA = 0.5f * (a + b + c + d);
    cH = 0.5f * (a + b - c - d);
    cV = 0.5f * (a - b + c - d);
    cD = 0.5f * (a - b - c + d);
}

__global__ __launch_bounds__(256)
void wavelet_main(const float* __restrict__ pred,
                  const float* __restrict__ target,
                  float* __restrict__ ws) {
    // [buf][inp][row][col] : exactly 64 KB
    __shared__ float lds[2][2][8][256];

    constexpr float W1 = 1.0f / (1.0f * 3.0f * (float)(N_BATCH * 256 * 256));
    constexpr float W2 = 1.0f / (2.0f * 3.0f * (float)(N_BATCH * 128 * 128));
    constexpr float W3 = 1.0f / (3.0f * 3.0f * (float)(N_BATCH * 64 * 64));

    const int t = threadIdx.x;
    const int w = t >> 6;        // wave 0..3
    const int l = t & 63;        // lane

    float acc = 0.0f;

    // --- stage tile T into buffer `buf`: wave w stages slots 4w..4w+3 ---
    // slot<8: pred row slot; slot>=8: target row slot-8. One instr = one row
    // (64 lanes x 16B = 1024B = 256 floats, contiguous in LDS).
    auto stage = [&](int T, int buf) {
        const int img   = T >> 7;
        const int rem   = T & 127;
        const int half  = rem & 1;
        const int strip = rem >> 1;
        const size_t base = (size_t)img * (512 * 512)
                          + (size_t)(strip * 8) * IMG_W
                          + half * 256 + l * 4;
        #pragma unroll
        for (int k = 0; k < 4; ++k) {
            const int slot = 4 * w + k;
            const int inp  = slot >> 3;
            const int row  = slot & 7;
            const float* g = (inp ? target : pred) + base + (size_t)row * IMG_W;
            __builtin_amdgcn_global_load_lds((gas_t)(const void*)g,
                                             (las_t)(void*)&lds[buf][inp][row][0],
                                             16, 0, 0);
        }
    };

    stage(blockIdx.x, 0);

    for (int it = 0; it < NT; ++it) {
        const int buf = it & 1;
        __syncthreads();   // drains this wave's DMA for tile `it` (issued last iter)
        if (it + 1 < NT) stage(blockIdx.x + (it + 1) * NBLK, buf ^ 1);

        if (w < 2) {       // waves 0-1 consume; wave-uniform branch
            const int g4  = l >> 2;     // 4-lane group 0..15
            const int sub = l & 3;      // position in 2x2 cA2 group
            const int br  = sub >> 1;   // block-row 0..1
            const int bc  = w * 32 + g4 * 2 + (sub & 1);   // block-col 0..63

            float4 P[4], Q[4];
            #pragma unroll
            for (int r = 0; r < 4; ++r) {
                P[r] = *(const float4*)&lds[buf][0][br * 4 + r][bc * 4];
                Q[r] = *(const float4*)&lds[buf][1][br * 4 + r][bc * 4];
            }

            // ---- level 1: 4 quads of the 4x4 block ----
            float s1 = 0.0f;
            float cA1p[4], cA1t[4];
            {
                float cA, cH, cV, cD, cAt, cHt, cVt, cDt;
                haar_quad(P[0].x, P[0].y, P[1].x, P[1].y, cA, cH, cV, cD);
                haar_quad(Q[0].x, Q[0].y, Q[1].x, Q[1].y, cAt, cHt, cVt, cDt);
                s1 += detail_term(cH, cHt, THR1) + detail_term(cV, cVt, THR1) + detail_term(cD, cDt, THR1);
                cA1p[0] = cA; cA1t[0] = cAt;

                haar_quad(P[0].z, P[0].w, P[1].z, P[1].w, cA, cH, cV, cD);
                haar_quad(Q[0].z, Q[0].w, Q[1].z, Q[1].w, cAt, cHt, cVt, cDt);
                s1 += detail_term(cH, cHt, THR1) + detail_term(cV, cVt, THR1) + detail_term(cD, cDt, THR1);
                cA1p[1] = cA; cA1t[1] = cAt;

                haar_quad(P[2].x, P[2].y, P[3].x, P[3].y, cA, cH, cV, cD);
                haar_quad(Q[2].x, Q[2].y, Q[3].x, Q[3].y, cAt, cHt, cVt, cDt);
                s1 += detail_term(cH, cHt, THR1) + detail_term(cV, cVt, THR1) + detail_term(cD, cDt, THR1);
                cA1p[2] = cA; cA1t[2] = cAt;

                haar_quad(P[2].z, P[2].w, P[3].z, P[3].w, cA, cH, cV, cD);
                haar_quad(Q[2].z, Q[2].w, Q[3].z, Q[3].w, cAt, cHt, cVt, cDt);
                s1 += detail_term(cH, cHt, THR1) + detail_term(cV, cVt, THR1) + detail_term(cD, cDt, THR1);
                cA1p[3] = cA; cA1t[3] = cAt;
            }

            // ---- level 2: one quad ----
            float s2, cA2p, cA2t;
            {
                float cH, cV, cD, cHt, cVt, cDt;
                haar_quad(cA1p[0], cA1p[1], cA1p[2], cA1p[3], cA2p, cH, cV, cD);
                haar_quad(cA1t[0], cA1t[1], cA1t[2], cA1t[3], cA2t, cHt, cVt, cDt);
                s2 = detail_term(cH, cHt, THR2) + detail_term(cV, cVt, THR2) + detail_term(cD, cDt, THR2);
            }

            // ---- level 3: 2x2 cA2 across the 4-lane group (R1 pattern) ----
            float s3;
            {
                float vp[4], vt[4];
                vp[sub]     = cA2p;                vt[sub]     = cA2t;
                vp[sub ^ 1] = __shfl_xor(cA2p, 1); vt[sub ^ 1] = __shfl_xor(cA2t, 1);
                vp[sub ^ 2] = __shfl_xor(cA2p, 2); vt[sub ^ 2] = __shfl_xor(cA2t, 2);
                vp[sub ^ 3] = __shfl_xor(cA2p, 3); vt[sub ^ 3] = __shfl_xor(cA2t, 3);
                float cA, cH, cV, cD, cAt, cHt, cVt, cDt;
                haar_quad(vp[0], vp[1], vp[2], vp[3], cA, cH, cV, cD);
                haar_quad(vt[0], vt[1], vt[2], vt[3], cAt, cHt, cVt, cDt);
                s3 = detail_term(cH, cHt, THR3) + detail_term(cV, cVt, THR3) + detail_term(cD, cDt, THR3);
            }
            const float w3 = (sub == 0) ? W3 : 0.0f;

            acc += W1 * s1 + W2 * s2 + w3 * s3;
        }
    }

    // wave reduction; one partial per wave (no extra LDS -> stay at 64 KB)
    #pragma unroll
    for (int off = 32; off > 0; off >>= 1)
        acc += __shfl_down(acc, off, 64);
    if (l == 0) ws[blockIdx.x * 4 + w] = acc;
}

__global__ __launch_bounds__(256)
void wavelet_reduce(const float* __restrict__ ws, float* __restrict__ out) {
    const int tidx = threadIdx.x;
    float v = 0.0f;
    #pragma unroll
    for (int k = 0; k < (NBLK * 4) / 256; ++k)
        v += ws[tidx + k * 256];

    #pragma unroll
    for (int off = 32; off > 0; off >>= 1)
        v += __shfl_down(v, off, 64);

    __shared__ float wave_sums[4];
    const int lane = tidx & 63;
    const int wave = tidx >> 6;
    if (lane == 0) wave_sums[wave] = v;
    __syncthreads();
    if (tidx == 0)
        out[0] = wave_sums[0] + wave_sums[1] + wave_sums[2] + wave_sums[3];
}

extern "C" void kernel_launch(void* const* d_in, const int* in_sizes, int n_in,
                              void* d_out, int out_size, void* d_ws, size_t ws_size,
                              hipStream_t stream) {
    const float* pred   = (const float*)d_in[0];
    const float* target = (const float*)d_in[1];
    float* out = (float*)d_out;
    float* ws  = (float*)d_ws;   // NBLK*4 floats = 16 KB

    wavelet_main<<<NBLK, 256, 0, stream>>>(pred, target, ws);
    wavelet_reduce<<<1, 256, 0, stream>>>(ws, out);
}

// Round 8
// 137.859 us; speedup vs baseline: 1.0545x; 1.0545x over previous
//
#include <hip/hip_runtime.h>

// WaveletLoss: 3-level Haar DWT + soft-threshold + weighted mean-abs-diff.
// B=64, C=1, H=W=512.
// R7 = R6 with compile fix: __builtin_nontemporal_load requires a NATIVE
// vector type (ext_vector_type), not HIP_vector_type<float,4>.
// Non-temporal load probe: wave owns 8x256 strip, every load instr = one
// contiguous 1024B row segment, all stream loads use the nt flag (no
// L2/LLC allocate) to test whether the pinned ~3.1 TB/s read wall is the
// L2 fill-on-read-miss path. 2048 blocks x 4 waves, 1 strip per wave.

#define IMG_W 512
#define N_BATCH 64

#define THR1 (50.0f / 255.0f)
#define THR2 (25.0f / 255.0f)
#define THR3 (12.5f / 255.0f)

#define NBLK 2048   // 2048 blocks * 4 waves = 8192 tiles of 8x256

typedef float v4f __attribute__((ext_vector_type(4)));

__device__ __forceinline__ float softthr(float x, float thr) {
    float m = fmaxf(fabsf(x) - thr, 0.0f);
    return copysignf(m, x);
}

__device__ __forceinline__ float detail_term(float p, float t, float thr) {
    return fabsf(softthr(p, thr) - softthr(t, thr));
}

__device__ __forceinline__ void haar_quad(float a, float b, float c, float d,
                                          float& cA, float& cH, float& cV, float& cD) {
    cA = 0.5f * (a + b + c + d);
    cH = 0.5f * (a + b - c - d);
    cV = 0.5f * (a - b + c - d);
    cD = 0.5f * (a - b - c + d);
}

__device__ __forceinline__ v4f ld4nt(const float* p) {
    return __builtin_nontemporal_load((const v4f*)p);
}

__global__ __launch_bounds__(256, 8)
void wavelet_main(const float* __restrict__ pred,
                  const float* __restrict__ target,
                  float* __restrict__ ws) {
    constexpr float W1 = 1.0f / (1.0f * 3.0f * (float)(N_BATCH * 256 * 256));
    constexpr float W2 = 1.0f / (2.0f * 3.0f * (float)(N_BATCH * 128 * 128));
    constexpr float W3 = 1.0f / (3.0f * 3.0f * (float)(N_BATCH * 64 * 64));

    const int T  = blockIdx.x * 4 + (threadIdx.x >> 6);   // tile id 0..8191
    const int li = threadIdx.x & 63;

    const int img   = T >> 7;
    const int rem   = T & 127;
    const int half  = rem & 1;
    const int strip = rem >> 1;               // 8-row strip 0..63

    const size_t off = (size_t)img * (512 * 512)
                     + (size_t)strip * 8 * IMG_W
                     + half * 256 + 4 * li;
    const float* pb = pred + off;
    const float* tb = target + off;

    // all 16 stream loads issued up front, non-temporal
    v4f P0 = ld4nt(pb);                 v4f P1 = ld4nt(pb + IMG_W);
    v4f P2 = ld4nt(pb + 2 * IMG_W);     v4f P3 = ld4nt(pb + 3 * IMG_W);
    v4f P4 = ld4nt(pb + 4 * IMG_W);     v4f P5 = ld4nt(pb + 5 * IMG_W);
    v4f P6 = ld4nt(pb + 6 * IMG_W);     v4f P7 = ld4nt(pb + 7 * IMG_W);
    v4f Q0 = ld4nt(tb);                 v4f Q1 = ld4nt(tb + IMG_W);
    v4f Q2 = ld4nt(tb + 2 * IMG_W);     v4f Q3 = ld4nt(tb + 3 * IMG_W);
    v4f Q4 = ld4nt(tb + 4 * IMG_W);     v4f Q5 = ld4nt(tb + 5 * IMG_W);
    v4f Q6 = ld4nt(tb + 6 * IMG_W);     v4f Q7 = ld4nt(tb + 7 * IMG_W);

    float s1 = 0.0f, s2 = 0.0f;
    float cA1p[4][2], cA1t[4][2];

    // ---- level 1: row-pairs (2rp, 2rp+1), two quads per pair (in-lane) ----
    {
        float cA, cH, cV, cD, cAt, cHt, cVt, cDt;

        #define L1_PAIR(a, b, qa, qb, rp)                                              \
        {                                                                              \
            haar_quad((a).x, (a).y, (b).x, (b).y, cA, cH, cV, cD);                     \
            haar_quad((qa).x, (qa).y, (qb).x, (qb).y, cAt, cHt, cVt, cDt);             \
            s1 += detail_term(cH, cHt, THR1) + detail_term(cV, cVt, THR1)              \
                + detail_term(cD, cDt, THR1);                                          \
            cA1p[rp][0] = cA; cA1t[rp][0] = cAt;                                       \
            haar_quad((a).z, (a).w, (b).z, (b).w, cA, cH, cV, cD);                     \
            haar_quad((qa).z, (qa).w, (qb).z, (qb).w, cAt, cHt, cVt, cDt);             \
            s1 += detail_term(cH, cHt, THR1) + detail_term(cV, cVt, THR1)              \
                + detail_term(cD, cDt, THR1);                                          \
            cA1p[rp][1] = cA; cA1t[rp][1] = cAt;                                       \
        }

        L1_PAIR(P0, P1, Q0, Q1, 0)
        L1_PAIR(P2, P3, Q2, Q3, 1)
        L1_PAIR(P4, P5, Q4, Q5, 2)
        L1_PAIR(P6, P7, Q6, Q7, 3)
        #undef L1_PAIR
    }

    // ---- level 2: two quads fully in-lane ----
    float cA2p[2], cA2t[2];
    {
        float cH, cV, cD, cHt, cVt, cDt;
        haar_quad(cA1p[0][0], cA1p[0][1], cA1p[1][0], cA1p[1][1], cA2p[0], cH, cV, cD);
        haar_quad(cA1t[0][0], cA1t[0][1], cA1t[1][0], cA1t[1][1], cA2t[0], cHt, cVt, cDt);
        s2 += detail_term(cH, cHt, THR2) + detail_term(cV, cVt, THR2) + detail_term(cD, cDt, THR2);
        haar_quad(cA1p[2][0], cA1p[2][1], cA1p[3][0], cA1p[3][1], cA2p[1], cH, cV, cD);
        haar_quad(cA1t[2][0], cA1t[2][1], cA1t[3][0], cA1t[3][1], cA2t[1], cHt, cVt, cDt);
        s2 += detail_term(cH, cHt, THR2) + detail_term(cV, cVt, THR2) + detail_term(cD, cDt, THR2);
    }

    // ---- level 3: horizontal neighbor via shfl_xor(1), vertical in-lane ----
    float s3;
    {
        const float bP = __shfl_xor(cA2p[0], 1);
        const float dP = __shfl_xor(cA2p[1], 1);
        const float bT = __shfl_xor(cA2t[0], 1);
        const float dT = __shfl_xor(cA2t[1], 1);
        float cA, cH, cV, cD, cAt, cHt, cVt, cDt;
        haar_quad(cA2p[0], bP, cA2p[1], dP, cA, cH, cV, cD);
        haar_quad(cA2t[0], bT, cA2t[1], dT, cAt, cHt, cVt, cDt);
        s3 = detail_term(cH, cHt, THR3) + detail_term(cV, cVt, THR3) + detail_term(cD, cDt, THR3);
    }
    const float w3 = (li & 1) ? 0.0f : W3;

    float acc = W1 * s1 + W2 * s2 + w3 * s3;

    // wave reduction (64 lanes)
    #pragma unroll
    for (int off = 32; off > 0; off >>= 1)
        acc += __shfl_down(acc, off, 64);

    __shared__ float wave_sums[4];
    const int lane_b = threadIdx.x & 63;
    const int wave_b = threadIdx.x >> 6;
    if (lane_b == 0) wave_sums[wave_b] = acc;
    __syncthreads();
    if (threadIdx.x == 0)
        ws[blockIdx.x] = wave_sums[0] + wave_sums[1] + wave_sums[2] + wave_sums[3];
}

__global__ __launch_bounds__(256)
void wavelet_reduce(const float* __restrict__ ws, float* __restrict__ out) {
    const int tidx = threadIdx.x;
    float v = 0.0f;
    #pragma unroll
    for (int k = 0; k < NBLK / 256; ++k)
        v += ws[tidx + k * 256];

    #pragma unroll
    for (int off = 32; off > 0; off >>= 1)
        v += __shfl_down(v, off, 64);

    __shared__ float wave_sums[4];
    const int lane = tidx & 63;
    const int wave = tidx >> 6;
    if (lane == 0) wave_sums[wave] = v;
    __syncthreads();
    if (tidx == 0)
        out[0] = wave_sums[0] + wave_sums[1] + wave_sums[2] + wave_sums[3];
}

extern "C" void kernel_launch(void* const* d_in, const int* in_sizes, int n_in,
                              void* d_out, int out_size, void* d_ws, size_t ws_size,
                              hipStream_t stream) {
    const float* pred   = (const float*)d_in[0];
    const float* target = (const float*)d_in[1];
    float* out = (float*)d_out;
    float* ws  = (float*)d_ws;   // NBLK floats = 8 KB

    wavelet_main<<<NBLK, 256, 0, stream>>>(pred, target, ws);
    wavelet_reduce<<<1, 256, 0, stream>>>(ws, out);
}